// Round 6
// baseline (417.066 us; speedup 1.0000x reference)
//
#include <hip/hip_runtime.h>
#include <hip/hip_bf16.h>

#define EPS 1e-6f
#define H 512
#define W 512
#define NB 8
#define NC 8
#define NS 7
#define LOG2E 1.4426950408889634f

__device__ __forceinline__ int refl(int t, int n) {
    if (t < 0) t = -t;
    if (t >= n) t = 2 * n - 2 - t;
    return t;
}

// ---------------- Kernel A: gaussian-smoothed max only (no u_sigma store) ---------
#define GW 256
#define GR 32
#define NBLK ((W / GW) * (H / GR))   // 32 slots per image

__global__ __launch_bounds__(256) void gauss_max_kernel(
    const float* __restrict__ est, const float* __restrict__ gauss,
    float* __restrict__ blockmax)
{
    const int tx = threadIdx.x, ty = threadIdx.y;
    const int x0 = blockIdx.x * GW;
    const int R  = blockIdx.y * GR + ty * 8;
    const int b  = blockIdx.z;
    const float* e = est + (size_t)b * H * W;
    const int c0 = x0 + tx * 4;

    const float g0 = sqrtf(gauss[0]);
    const float g1 = sqrtf(gauss[6]);
    const float g2 = sqrtf(gauss[12]);

    float4 h0, h1, h2, h3, h4;
    float m = 0.f;

#pragma unroll
    for (int k = 0; k < 12; k++) {
        const float* row = e + refl(R - 2 + k, H) * W;
        float4 v = *(const float4*)&row[c0];
        float em2 = __shfl_up(v.z, 1);
        float em1 = __shfl_up(v.w, 1);
        float ep1 = __shfl_down(v.x, 1);
        float ep2 = __shfl_down(v.y, 1);
        if (tx == 0) {
            if (x0 == 0) { em2 = v.z; em1 = v.y; }
            else         { em2 = row[c0 - 2]; em1 = row[c0 - 1]; }
        }
        if (tx == 63) {
            if (x0 + GW == W) { ep1 = v.z; ep2 = v.y; }
            else              { ep1 = row[c0 + 4]; ep2 = row[c0 + 5]; }
        }
        float4 hc;
        hc.x = g0 * (em2 + v.z) + g1 * (em1 + v.y) + g2 * v.x;
        hc.y = g0 * (em1 + v.w) + g1 * (v.x + v.z) + g2 * v.y;
        hc.z = g0 * (v.x + ep1) + g1 * (v.y + v.w) + g2 * v.z;
        hc.w = g0 * (v.y + ep2) + g1 * (v.z + ep1) + g2 * v.w;
        h0 = h1; h1 = h2; h2 = h3; h3 = h4; h4 = hc;
        if (k >= 4) {
            float ux = g0 * (h0.x + h4.x) + g1 * (h1.x + h3.x) + g2 * h2.x;
            float uy = g0 * (h0.y + h4.y) + g1 * (h1.y + h3.y) + g2 * h2.y;
            float uz = g0 * (h0.z + h4.z) + g1 * (h1.z + h3.z) + g2 * h2.z;
            float uw = g0 * (h0.w + h4.w) + g1 * (h1.w + h3.w) + g2 * h2.w;
            m = fmaxf(m, fmaxf(fmaxf(ux, uy), fmaxf(uz, uw)));
        }
    }

#pragma unroll
    for (int off = 32; off > 0; off >>= 1)
        m = fmaxf(m, __shfl_xor(m, off, 64));
    __shared__ float wm[4];
    if (tx == 0) wm[ty] = m;
    __syncthreads();
    if (tx == 0 && ty == 0) {
        float mm = fmaxf(fmaxf(wm[0], wm[1]), fmaxf(wm[2], wm[3]));
        blockmax[b * NBLK + blockIdx.y * gridDim.x + blockIdx.x] = mm;
    }
}

// ---------------- Kernel B: register-streaming stage, 1 wave = 64-col band --------
// Band: 64 lanes, outputs lanes 3..60 (58 cols). 9 bands cover 512 (522 >= 512).
// March down rows; all state in registers; zero LDS, zero barriers.
#define SLAB 16
#define BANDW 58
#define NBANDS 9

__global__ __launch_bounds__(64) void stage_kernel(
    const float* __restrict__ est, const float* __restrict__ noisy,
    const float* __restrict__ blockmax,
    const float* __restrict__ filt,  // [8][9] this stage
    const float* __restrict__ wv, const float* __restrict__ bv,
    const float* __restrict__ lamp, const float* __restrict__ gatep,
    const float* __restrict__ gauss,
    float* __restrict__ out)
{
    const int l = threadIdx.x;
    const int band = blockIdx.x;
    const int R = blockIdx.y * SLAB;
    const int b = blockIdx.z;
    const int c = band * BANDW - 3 + l;          // this lane's column (may be outside)
    const int cl = refl(c, W);                   // in-bounds load column
    const int ccl = c < 0 ? 0 : (c > W - 1 ? W - 1 : c);

    const float* e   = est   + (size_t)b * H * W;
    const float* nz  = noisy + (size_t)b * H * W;
    float*       op  = out   + (size_t)b * H * W;

    // uniform parameters (scalar loads)
    float fco[NC][9];
#pragma unroll
    for (int ch = 0; ch < NC; ch++)
#pragma unroll
        for (int k = 0; k < 9; k++) fco[ch][k] = filt[ch * 9 + k];
    float w2[NC], b2[NC];
#pragma unroll
    for (int ch = 0; ch < NC; ch++) {
        w2[ch] = wv[ch] * (2.f * LOG2E);
        b2[ch] = bv[ch] * (2.f * LOG2E);
    }
    const float g0 = sqrtf(gauss[0]);
    const float g1 = sqrtf(gauss[6]);
    const float g2 = sqrtf(gauss[12]);
    const float lam = lamp[0];
    const float g = __builtin_amdgcn_rcpf(1.f + __builtin_amdgcn_exp2f(-gatep[0] * LOG2E));

    float m = blockmax[b * NBLK + (l & 31)];
#pragma unroll
    for (int off = 16; off > 0; off >>= 1)
        m = fmaxf(m, __shfl_xor(m, off, 64));
    const float dinv = __builtin_amdgcn_rcpf(fmaxf(m, EPS));

    // loop-invariant reflect selects at image x-edges
    const bool cm0 = (c == 0), cm1 = (c == 1), cp0 = (c == W - 1), cp1 = (c == W - 2);
    const bool c_in = (c >= 0) && (c < W);
    const bool c_st = (l >= 3) && (l <= 60) && (c < W);

    // load virtual row vr: value + reflect-fixed x-neighbors + h-pass result
    auto loadrow = [&](int vr, float& v, float& m1, float& p1, float& hv) {
        v = e[(size_t)refl(vr, H) * W + cl];
        float m1r = __shfl_up(v, 1), p1r = __shfl_down(v, 1);
        float m2r = __shfl_up(v, 2), p2r = __shfl_down(v, 2);
        m1 = cm0 ? p1r : m1r;
        float m2 = cm0 ? p2r : (cm1 ? v : m2r);
        p1 = cp0 ? m1r : p1r;
        float p2 = cp0 ? m2r : (cp1 ? v : p2r);
        hv = g0 * (m2 + p2) + g1 * (m1 + p1) + g2 * v;
    };

    // rolling windows
    float ev[4], em[4], ep[4];   // est rows t-1..t+2 (after shift)
    float h[5];                  // h-pass rows t-2..t+2 (after shift)

    // prologue rows R-3..R: h[1..4]; ev/em/ep[1..3] = rows R-2..R
    {
        float v, m1, p1, hv;
        loadrow(R - 3, v, m1, p1, hv); h[1] = hv;
        loadrow(R - 2, v, m1, p1, hv); h[2] = hv; ev[1] = v; em[1] = m1; ep[1] = p1;
        loadrow(R - 1, v, m1, p1, hv); h[3] = hv; ev[2] = v; em[2] = m1; ep[2] = p1;
        loadrow(R - 0, v, m1, p1, hv); h[4] = hv; ev[3] = v; em[3] = m1; ep[3] = p1;
    }
    ev[0] = 0.f; em[0] = 0.f; ep[0] = 0.f; h[0] = 0.f;

    float acc0 = 0.f, acc1 = 0.f, iw_prev = 0.f;

#pragma unroll 3
    for (int i = 0; i < SLAB + 2; ++i) {
        const int t = R - 1 + i;

        float v, m1, p1, hnew;
        loadrow(t + 2, v, m1, p1, hnew);

        // prefetch noisy for output row t-1
        const int orow = t - 1 < 0 ? 0 : (t - 1 > H - 1 ? H - 1 : t - 1);
        const float n0 = nz[(size_t)orow * W + ccl];

        h[0] = h[1]; h[1] = h[2]; h[2] = h[3]; h[3] = h[4]; h[4] = hnew;
        float iw = g0 * (h[0] + h[4]) + g1 * (h[1] + h[3]) + g2 * h[2];
        iw = fmaxf(iw * dinv, EPS);
        if (!c_in || t < 0 || t > H - 1) iw = 0.f;   // zero-pad of transpose conv

        ev[0] = ev[1]; em[0] = em[1]; ep[0] = ep[1];
        ev[1] = ev[2]; em[1] = em[2]; ep[1] = ep[2];
        ev[2] = ev[3]; em[2] = em[3]; ep[2] = ep[3];
        ev[3] = v;     em[3] = m1;    ep[3] = p1;

        // analysis conv (est rows t-1..t+1) -> z per channel -> synthesis partials
        float U0 = 0.f, U1 = 0.f, U2 = 0.f;
        float V0 = 0.f, V1 = 0.f, V2 = 0.f;
        float W0 = 0.f, W1 = 0.f, W2 = 0.f;
#pragma unroll
        for (int ch = 0; ch < NC; ch++) {
            float r = fco[ch][0] * em[0] + fco[ch][1] * ev[0] + fco[ch][2] * ep[0]
                    + fco[ch][3] * em[1] + fco[ch][4] * ev[1] + fco[ch][5] * ep[1]
                    + fco[ch][6] * em[2] + fco[ch][7] * ev[2] + fco[ch][8] * ep[2];
            float a = __builtin_amdgcn_exp2f(r * w2[ch] + b2[ch]);
            float z = iw * (1.f - 2.f * __builtin_amdgcn_rcpf(a + 1.f));
            U0 += fco[ch][0] * z; V0 += fco[ch][1] * z; W0 += fco[ch][2] * z;
            U1 += fco[ch][3] * z; V1 += fco[ch][4] * z; W1 += fco[ch][5] * z;
            U2 += fco[ch][6] * z; V2 += fco[ch][7] * z; W2 += fco[ch][8] * z;
        }

        // q[ky] for this z-row; x-neighbors via shfl (zero-pad handled by iw=0 cols)
        float q0 = __shfl_up(U0, 1) + V0 + __shfl_down(W0, 1);
        float q1 = __shfl_up(U1, 1) + V1 + __shfl_down(W1, 1);
        float q2 = __shfl_up(U2, 1) + V2 + __shfl_down(W2, 1);

        float diff = acc0 + q2;    // diff for row t-1 complete
        acc0 = acc1 + q1;
        acc1 = q0;

        if (i >= 2 && c_st) {
            float eo = ev[0];      // est row t-1
            float fg = (eo - n0) * __builtin_amdgcn_rcpf(eo * eo + EPS);
            float est2 = eo - diff - lam * iw_prev * fg;
            float en = est2 + g * (n0 - est2);
            en = fminf(fmaxf(en, EPS), 1.f);
            op[(size_t)(t - 1) * W + c] = en;
        }
        iw_prev = iw;
    }
}

extern "C" void kernel_launch(void* const* d_in, const int* in_sizes, int n_in,
                              void* d_out, int out_size, void* d_ws, size_t ws_size,
                              hipStream_t stream)
{
    const float* noisy   = (const float*)d_in[0];
    const float* filters = (const float*)d_in[1];  // [7][8][1][3][3]
    const float* wv      = (const float*)d_in[2];  // [7][8]
    const float* bv      = (const float*)d_in[3];  // [7][8]
    const float* lam     = (const float*)d_in[4];  // [7]
    const float* gate    = (const float*)d_in[5];  // [7]
    const float* gauss   = (const float*)d_in[6];  // [25]
    float* out = (float*)d_out;

    char* ws = (char*)d_ws;
    float* ws0      = (float*)ws;                    // 8 MB ping buffer
    float* blockmax = (float*)(ws + (8u << 20));     // 32*8 floats, rewritten each stage

    const float* cur = noisy;
    for (int s = 0; s < NS; s++) {
        float* nxt = (s % 2 == 0) ? out : ws0;  // odd stage count -> final lands in out
        gauss_max_kernel<<<dim3(W / GW, H / GR, NB), dim3(64, 4), 0, stream>>>(
            cur, gauss, blockmax);
        stage_kernel<<<dim3(NBANDS, H / SLAB, NB), dim3(64), 0, stream>>>(
            cur, noisy, blockmax,
            filters + s * NC * 9, wv + s * NC, bv + s * NC, lam + s, gate + s, gauss, nxt);
        cur = nxt;
    }
}

// Round 7
// 378.883 us; speedup vs baseline: 1.1008x; 1.1008x over previous
//
#include <hip/hip_runtime.h>
#include <hip/hip_bf16.h>

#define EPS 1e-6f
#define H 512
#define W 512
#define NB 8
#define NC 8
#define NS 7
#define LOG2E 1.4426950408889634f

__device__ __forceinline__ int refl(int t, int n) {
    if (t < 0) t = -t;
    if (t >= n) t = 2 * n - 2 - t;
    return t;
}

// ---------------- Kernel A: gaussian-smoothed max only ----------------------------
#define GW 256
#define GR 8
#define NBLK ((W / GW) * (H / GR))   // 128 slots per image

__global__ __launch_bounds__(256) void gauss_max_kernel(
    const float* __restrict__ est, const float* __restrict__ gauss,
    float* __restrict__ blockmax)
{
    const int tx = threadIdx.x, ty = threadIdx.y;
    const int x0 = blockIdx.x * GW;
    const int R  = blockIdx.y * GR + ty * 2;     // this wave: output rows R, R+1
    const int b  = blockIdx.z;
    const float* e = est + (size_t)b * H * W;
    const int c0 = x0 + tx * 4;

    const float g0 = sqrtf(gauss[0]);
    const float g1 = sqrtf(gauss[6]);
    const float g2 = sqrtf(gauss[12]);

    float4 h0, h1, h2, h3, h4;
    float m = 0.f;

#pragma unroll
    for (int k = 0; k < 6; k++) {
        const float* row = e + refl(R - 2 + k, H) * W;
        float4 v = *(const float4*)&row[c0];
        float em2 = __shfl_up(v.z, 1);
        float em1 = __shfl_up(v.w, 1);
        float ep1 = __shfl_down(v.x, 1);
        float ep2 = __shfl_down(v.y, 1);
        if (tx == 0) {
            if (x0 == 0) { em2 = v.z; em1 = v.y; }
            else         { em2 = row[c0 - 2]; em1 = row[c0 - 1]; }
        }
        if (tx == 63) {
            if (x0 + GW == W) { ep1 = v.z; ep2 = v.y; }
            else              { ep1 = row[c0 + 4]; ep2 = row[c0 + 5]; }
        }
        float4 hc;
        hc.x = g0 * (em2 + v.z) + g1 * (em1 + v.y) + g2 * v.x;
        hc.y = g0 * (em1 + v.w) + g1 * (v.x + v.z) + g2 * v.y;
        hc.z = g0 * (v.x + ep1) + g1 * (v.y + v.w) + g2 * v.z;
        hc.w = g0 * (v.y + ep2) + g1 * (v.z + ep1) + g2 * v.w;
        h0 = h1; h1 = h2; h2 = h3; h3 = h4; h4 = hc;
        if (k >= 4) {
            float ux = g0 * (h0.x + h4.x) + g1 * (h1.x + h3.x) + g2 * h2.x;
            float uy = g0 * (h0.y + h4.y) + g1 * (h1.y + h3.y) + g2 * h2.y;
            float uz = g0 * (h0.z + h4.z) + g1 * (h1.z + h3.z) + g2 * h2.z;
            float uw = g0 * (h0.w + h4.w) + g1 * (h1.w + h3.w) + g2 * h2.w;
            m = fmaxf(m, fmaxf(fmaxf(ux, uy), fmaxf(uz, uw)));
        }
    }

#pragma unroll
    for (int off = 32; off > 0; off >>= 1)
        m = fmaxf(m, __shfl_xor(m, off, 64));
    __shared__ float wm[4];
    if (tx == 0) wm[ty] = m;
    __syncthreads();
    if (tx == 0 && ty == 0) {
        float mm = fmaxf(fmaxf(wm[0], wm[1]), fmaxf(wm[2], wm[3]));
        blockmax[b * NBLK + blockIdx.y * gridDim.x + blockIdx.x] = mm;
    }
}

// ---------------- Kernel B: register-streaming stage ------------------------------
// 1 wave = 64-col band (outputs lanes 3..60), marching SLAB rows. Zero LDS.
// Templated: CE = column-edge band, RE = row-edge slab; interior path has no
// reflect selects, no row-refl address math, walking pointers only.
#define SLAB 8
#define BANDW 58
#define NBANDS 9

template<bool CE, bool RE>
__device__ __forceinline__ void run_band(
    const float* __restrict__ e, const float* __restrict__ nz,
    float* __restrict__ op,
    const float* __restrict__ filt, const float* __restrict__ wv,
    const float* __restrict__ bv,
    float lam, float g, float dinv, float g0, float g1, float g2,
    int l, int band, int R)
{
    const int c = band * BANDW - 3 + l;
    const int cl = CE ? refl(c, W) : c;
    const int cc = CE ? (c < 0 ? 0 : (c > W - 1 ? W - 1 : c)) : c;

    // uniform parameters -> scalar regs
    float fco[NC][9];
#pragma unroll
    for (int ch = 0; ch < NC; ch++)
#pragma unroll
        for (int k = 0; k < 9; k++) fco[ch][k] = filt[ch * 9 + k];
    float w2[NC], b2[NC];
#pragma unroll
    for (int ch = 0; ch < NC; ch++) {
        w2[ch] = wv[ch] * (2.f * LOG2E);
        b2[ch] = bv[ch] * (2.f * LOG2E);
    }

    const bool cm0 = CE && (c == 0), cm1 = CE && (c == 1);
    const bool cp0 = CE && (c == W - 1), cp1 = CE && (c == W - 2);
    const bool c_in = !CE || ((c >= 0) && (c < W));
    const bool c_st = (l >= 3) && (l <= 60) && (!CE || c < W);

    const float* pe = e  + (RE ? (size_t)0 : (size_t)(R - 3) * W) + cl;
    const float* pn = nz + (RE ? (size_t)0 : (size_t)(R - 2) * W) + cc;
    int vr_next = R - 3;

    auto raw = [&]() -> float {
        float v;
        if constexpr (RE) {
            v = e[(size_t)refl(vr_next, H) * W + cl];
            vr_next++;
        } else {
            v = *pe; pe += W;
        }
        return v;
    };

    auto hpass = [&](float v, float& m1, float& p1) -> float {
        float m1r = __shfl_up(v, 1), p1r = __shfl_down(v, 1);
        float m2r = __shfl_up(v, 2), p2r = __shfl_down(v, 2);
        float m2, p2;
        if constexpr (CE) {
            m1 = cm0 ? p1r : m1r;
            m2 = cm0 ? p2r : (cm1 ? v : m2r);
            p1 = cp0 ? m1r : p1r;
            p2 = cp0 ? m2r : (cp1 ? v : p2r);
        } else { m1 = m1r; p1 = p1r; m2 = m2r; p2 = p2r; }
        return g0 * (m2 + p2) + g1 * (m1 + p1) + g2 * v;
    };

    float ev[4], em[4], ep[4], h[5];
    {
        float v, m1, p1;
        v = raw(); h[1] = hpass(v, m1, p1);
        v = raw(); h[2] = hpass(v, m1, p1); ev[1] = v; em[1] = m1; ep[1] = p1;
        v = raw(); h[3] = hpass(v, m1, p1); ev[2] = v; em[2] = m1; ep[2] = p1;
        v = raw(); h[4] = hpass(v, m1, p1); ev[3] = v; em[3] = m1; ep[3] = p1;
    }
    float vpre = raw();   // row R+1 prefetched
    ev[0] = 0.f; em[0] = 0.f; ep[0] = 0.f; h[0] = 0.f;

    float acc0 = 0.f, acc1 = 0.f, iw_prev = 0.f;

#pragma unroll 2
    for (int i = 0; i < SLAB + 2; ++i) {
        const int t = R - 1 + i;

        float v = vpre;
        vpre = raw();            // prefetch row t+3 (one iteration ahead)

        float n0;
        if constexpr (RE) {
            int orow = t - 1 < 0 ? 0 : (t - 1 > H - 1 ? H - 1 : t - 1);
            n0 = nz[(size_t)orow * W + cc];
        } else {
            n0 = *pn; pn += W;
        }

        float m1, p1;
        float hnew = hpass(v, m1, p1);

        h[0] = h[1]; h[1] = h[2]; h[2] = h[3]; h[3] = h[4]; h[4] = hnew;
        float iw = g0 * (h[0] + h[4]) + g1 * (h[1] + h[3]) + g2 * h[2];
        iw = fmaxf(iw * dinv, EPS);
        if constexpr (CE || RE) {
            bool rin = !RE || (t >= 0 && t <= H - 1);
            if (!(c_in && rin)) iw = 0.f;   // zero-pad of transpose conv
        }

        ev[0] = ev[1]; em[0] = em[1]; ep[0] = ep[1];
        ev[1] = ev[2]; em[1] = em[2]; ep[1] = ep[2];
        ev[2] = ev[3]; em[2] = em[3]; ep[2] = ep[3];
        ev[3] = v;     em[3] = m1;    ep[3] = p1;

        float U0 = 0.f, U1 = 0.f, U2 = 0.f;
        float V0 = 0.f, V1 = 0.f, V2 = 0.f;
        float W0 = 0.f, W1 = 0.f, W2 = 0.f;
#pragma unroll
        for (int ch = 0; ch < NC; ch++) {
            float r = fco[ch][0] * em[0] + fco[ch][1] * ev[0] + fco[ch][2] * ep[0]
                    + fco[ch][3] * em[1] + fco[ch][4] * ev[1] + fco[ch][5] * ep[1]
                    + fco[ch][6] * em[2] + fco[ch][7] * ev[2] + fco[ch][8] * ep[2];
            float a = __builtin_amdgcn_exp2f(r * w2[ch] + b2[ch]);
            float z = iw * (1.f - 2.f * __builtin_amdgcn_rcpf(a + 1.f));
            U0 += fco[ch][0] * z; V0 += fco[ch][1] * z; W0 += fco[ch][2] * z;
            U1 += fco[ch][3] * z; V1 += fco[ch][4] * z; W1 += fco[ch][5] * z;
            U2 += fco[ch][6] * z; V2 += fco[ch][7] * z; W2 += fco[ch][8] * z;
        }

        float q0 = __shfl_up(U0, 1) + V0 + __shfl_down(W0, 1);
        float q1 = __shfl_up(U1, 1) + V1 + __shfl_down(W1, 1);
        float q2 = __shfl_up(U2, 1) + V2 + __shfl_down(W2, 1);

        float diff = acc0 + q2;    // diff for row t-1 complete
        acc0 = acc1 + q1;
        acc1 = q0;

        if (i >= 2 && c_st) {
            float eo = ev[0];      // est row t-1
            float fg = (eo - n0) * __builtin_amdgcn_rcpf(eo * eo + EPS);
            float est2 = eo - diff - lam * iw_prev * fg;
            float en = est2 + g * (n0 - est2);
            en = fminf(fmaxf(en, EPS), 1.f);
            op[(size_t)(t - 1) * W + c] = en;
        }
        iw_prev = iw;
    }
}

__global__ __launch_bounds__(64) void stage_kernel(
    const float* __restrict__ est, const float* __restrict__ noisy,
    const float* __restrict__ blockmax,
    const float* __restrict__ filt,
    const float* __restrict__ wv, const float* __restrict__ bv,
    const float* __restrict__ lamp, const float* __restrict__ gatep,
    const float* __restrict__ gauss,
    float* __restrict__ out)
{
    const int l = threadIdx.x;
    const int band = blockIdx.x;
    const int R = blockIdx.y * SLAB;
    const int b = blockIdx.z;

    const float* e  = est   + (size_t)b * H * W;
    const float* nz = noisy + (size_t)b * H * W;
    float*       op = out   + (size_t)b * H * W;

    const float g0 = sqrtf(gauss[0]);
    const float g1 = sqrtf(gauss[6]);
    const float g2 = sqrtf(gauss[12]);
    const float lam = lamp[0];
    const float g = __builtin_amdgcn_rcpf(1.f + __builtin_amdgcn_exp2f(-gatep[0] * LOG2E));

    float m = fmaxf(blockmax[b * NBLK + l], blockmax[b * NBLK + 64 + l]);
#pragma unroll
    for (int off = 32; off > 0; off >>= 1)
        m = fmaxf(m, __shfl_xor(m, off, 64));
    const float dinv = __builtin_amdgcn_rcpf(fmaxf(m, EPS));

    const bool ce = (band == 0) || (band == NBANDS - 1);
    const bool re = (blockIdx.y == 0) || (blockIdx.y == gridDim.y - 1);

    if (!ce && !re)      run_band<false, false>(e, nz, op, filt, wv, bv, lam, g, dinv, g0, g1, g2, l, band, R);
    else if (!ce)        run_band<false, true >(e, nz, op, filt, wv, bv, lam, g, dinv, g0, g1, g2, l, band, R);
    else if (!re)        run_band<true,  false>(e, nz, op, filt, wv, bv, lam, g, dinv, g0, g1, g2, l, band, R);
    else                 run_band<true,  true >(e, nz, op, filt, wv, bv, lam, g, dinv, g0, g1, g2, l, band, R);
}

extern "C" void kernel_launch(void* const* d_in, const int* in_sizes, int n_in,
                              void* d_out, int out_size, void* d_ws, size_t ws_size,
                              hipStream_t stream)
{
    const float* noisy   = (const float*)d_in[0];
    const float* filters = (const float*)d_in[1];  // [7][8][1][3][3]
    const float* wv      = (const float*)d_in[2];  // [7][8]
    const float* bv      = (const float*)d_in[3];  // [7][8]
    const float* lam     = (const float*)d_in[4];  // [7]
    const float* gate    = (const float*)d_in[5];  // [7]
    const float* gauss   = (const float*)d_in[6];  // [25]
    float* out = (float*)d_out;

    char* ws = (char*)d_ws;
    float* ws0      = (float*)ws;                    // 8 MB ping buffer
    float* blockmax = (float*)(ws + (8u << 20));     // 128*8 floats, rewritten each stage

    const float* cur = noisy;
    for (int s = 0; s < NS; s++) {
        float* nxt = (s % 2 == 0) ? out : ws0;  // odd stage count -> final lands in out
        gauss_max_kernel<<<dim3(W / GW, H / GR, NB), dim3(64, 4), 0, stream>>>(
            cur, gauss, blockmax);
        stage_kernel<<<dim3(NBANDS, H / SLAB, NB), dim3(64), 0, stream>>>(
            cur, noisy, blockmax,
            filters + s * NC * 9, wv + s * NC, bv + s * NC, lam + s, gate + s, gauss, nxt);
        cur = nxt;
    }
}

// Round 8
// 329.226 us; speedup vs baseline: 1.2668x; 1.1508x over previous
//
#include <hip/hip_runtime.h>
#include <hip/hip_bf16.h>

#define EPS 1e-6f
#define H 512
#define W 512
#define NB 8
#define NC 8
#define NS 7
#define LOG2E 1.4426950408889634f

__device__ __forceinline__ int refl(int t, int n) {
    if (t < 0) t = -t;
    if (t >= n) t = 2 * n - 2 - t;
    return t;
}

// ---------------- Kernel A: gaussian-smoothed max only ----------------------------
#define GW 256
#define GR 8
#define NBLK ((W / GW) * (H / GR))   // 128 slots per image

__global__ __launch_bounds__(256) void gauss_max_kernel(
    const float* __restrict__ est, const float* __restrict__ gauss,
    float* __restrict__ blockmax)
{
    const int tx = threadIdx.x, ty = threadIdx.y;
    const int x0 = blockIdx.x * GW;
    const int R  = blockIdx.y * GR + ty * 2;     // this wave: output rows R, R+1
    const int b  = blockIdx.z;
    const float* e = est + (size_t)b * H * W;
    const int c0 = x0 + tx * 4;

    const float g0 = sqrtf(gauss[0]);
    const float g1 = sqrtf(gauss[6]);
    const float g2 = sqrtf(gauss[12]);

    float4 h0, h1, h2, h3, h4;
    float m = 0.f;

#pragma unroll
    for (int k = 0; k < 6; k++) {
        const float* row = e + refl(R - 2 + k, H) * W;
        float4 v = *(const float4*)&row[c0];
        float em2 = __shfl_up(v.z, 1);
        float em1 = __shfl_up(v.w, 1);
        float ep1 = __shfl_down(v.x, 1);
        float ep2 = __shfl_down(v.y, 1);
        if (tx == 0) {
            if (x0 == 0) { em2 = v.z; em1 = v.y; }
            else         { em2 = row[c0 - 2]; em1 = row[c0 - 1]; }
        }
        if (tx == 63) {
            if (x0 + GW == W) { ep1 = v.z; ep2 = v.y; }
            else              { ep1 = row[c0 + 4]; ep2 = row[c0 + 5]; }
        }
        float4 hc;
        hc.x = g0 * (em2 + v.z) + g1 * (em1 + v.y) + g2 * v.x;
        hc.y = g0 * (em1 + v.w) + g1 * (v.x + v.z) + g2 * v.y;
        hc.z = g0 * (v.x + ep1) + g1 * (v.y + v.w) + g2 * v.z;
        hc.w = g0 * (v.y + ep2) + g1 * (v.z + ep1) + g2 * v.w;
        h0 = h1; h1 = h2; h2 = h3; h3 = h4; h4 = hc;
        if (k >= 4) {
            float ux = g0 * (h0.x + h4.x) + g1 * (h1.x + h3.x) + g2 * h2.x;
            float uy = g0 * (h0.y + h4.y) + g1 * (h1.y + h3.y) + g2 * h2.y;
            float uz = g0 * (h0.z + h4.z) + g1 * (h1.z + h3.z) + g2 * h2.z;
            float uw = g0 * (h0.w + h4.w) + g1 * (h1.w + h3.w) + g2 * h2.w;
            m = fmaxf(m, fmaxf(fmaxf(ux, uy), fmaxf(uz, uw)));
        }
    }

#pragma unroll
    for (int off = 32; off > 0; off >>= 1)
        m = fmaxf(m, __shfl_xor(m, off, 64));
    __shared__ float wm[4];
    if (tx == 0) wm[ty] = m;
    __syncthreads();
    if (tx == 0 && ty == 0) {
        float mm = fmaxf(fmaxf(wm[0], wm[1]), fmaxf(wm[2], wm[3]));
        blockmax[b * NBLK + blockIdx.y * gridDim.x + blockIdx.x] = mm;
    }
}

// ---------------- Kernel B: register-streaming stage ------------------------------
// 1 wave = 64-col band (outputs lanes 3..60), marching SLAB rows. Zero LDS.
// Deep prefetch: est & noisy rows loaded 3 iterations before first use.
// Synthesis accumulators kept in (U,V,W) space -> only 2 shfls per row.
#define SLAB 8
#define BANDW 58
#define NBANDS 9

template<bool CE, bool RE>
__device__ __forceinline__ void run_band(
    const float* __restrict__ e, const float* __restrict__ nz,
    float* __restrict__ op,
    const float* __restrict__ filt, const float* __restrict__ wv,
    const float* __restrict__ bv,
    float lam, float g, float dinv, float g0, float g1, float g2,
    int l, int band, int R)
{
    const int c = band * BANDW - 3 + l;
    const int cl = CE ? refl(c, W) : c;
    const int cc = CE ? (c < 0 ? 0 : (c > W - 1 ? W - 1 : c)) : c;

    // uniform parameters -> scalar regs
    float fco[NC][9];
#pragma unroll
    for (int ch = 0; ch < NC; ch++)
#pragma unroll
        for (int k = 0; k < 9; k++) fco[ch][k] = filt[ch * 9 + k];
    float w2[NC], b2[NC];
#pragma unroll
    for (int ch = 0; ch < NC; ch++) {
        w2[ch] = wv[ch] * (2.f * LOG2E);
        b2[ch] = bv[ch] * (2.f * LOG2E);
    }

    const bool cm0 = CE && (c == 0), cm1 = CE && (c == 1);
    const bool cp0 = CE && (c == W - 1), cp1 = CE && (c == W - 2);
    const bool c_in = !CE || ((c >= 0) && (c < W));
    const bool c_st = (l >= 3) && (l <= 60) && (!CE || c < W);

    // est row loader (next row to load: starts at R-3)
    const float* pe = e + (RE ? (size_t)0 : (size_t)(R - 3) * W) + cl;
    int vr_next = R - 3;
    auto lde = [&]() -> float {
        if constexpr (RE) {
            float v = e[(size_t)refl(vr_next, H) * W + cl];
            vr_next++;
            return v;
        } else {
            float v = *pe; pe += W; return v;
        }
    };

    // noisy row loader (next row to load: starts at R-2)
    const float* pn = nz + (RE ? (size_t)0 : (size_t)(R - 2) * W) + cc;
    int nr_next = R - 2;
    auto ldn = [&]() -> float {
        if constexpr (RE) {
            int r = nr_next < 0 ? 0 : (nr_next > H - 1 ? H - 1 : nr_next);
            nr_next++;
            return nz[(size_t)r * W + cc];
        } else {
            float v = *pn; pn += W; return v;
        }
    };

    auto hpass = [&](float v, float& m1, float& p1) -> float {
        float m1r = __shfl_up(v, 1), p1r = __shfl_down(v, 1);
        float m2r = __shfl_up(v, 2), p2r = __shfl_down(v, 2);
        float m2, p2;
        if constexpr (CE) {
            m1 = cm0 ? p1r : m1r;
            m2 = cm0 ? p2r : (cm1 ? v : m2r);
            p1 = cp0 ? m1r : p1r;
            p2 = cp0 ? m2r : (cp1 ? v : p2r);
        } else { m1 = m1r; p1 = p1r; m2 = m2r; p2 = p2r; }
        return g0 * (m2 + p2) + g1 * (m1 + p1) + g2 * v;
    };

    // prologue: rows R-3..R processed, rows R+1..R+3 prefetched
    float ev[4], em[4], ep[4], h[5];
    {
        float v, m1, p1;
        v = lde(); h[1] = hpass(v, m1, p1);
        v = lde(); h[2] = hpass(v, m1, p1); ev[1] = v; em[1] = m1; ep[1] = p1;
        v = lde(); h[3] = hpass(v, m1, p1); ev[2] = v; em[2] = m1; ep[2] = p1;
        v = lde(); h[4] = hpass(v, m1, p1); ev[3] = v; em[3] = m1; ep[3] = p1;
    }
    float vq0 = lde(), vq1 = lde(), vq2 = lde();   // est rows R+1, R+2, R+3
    float nq0 = ldn(), nq1 = ldn(), nq2 = ldn();   // noisy rows R-2, R-1, R
    ev[0] = 0.f; em[0] = 0.f; ep[0] = 0.f; h[0] = 0.f;

    float aU0 = 0.f, aV0 = 0.f, aW0 = 0.f;
    float aU1 = 0.f, aV1 = 0.f, aW1 = 0.f;
    float iw_prev = 0.f;

#pragma unroll 2
    for (int i = 0; i < SLAB + 2; ++i) {
        const int t = R - 1 + i;

        // pop prefetched values; refill queues 3 iterations ahead
        float v = vq0;  vq0 = vq1; vq1 = vq2; vq2 = lde();   // loads est row t+5
        float n0 = nq0; nq0 = nq1; nq1 = nq2; nq2 = ldn();   // loads noisy row t+2

        float m1, p1;
        float hnew = hpass(v, m1, p1);

        h[0] = h[1]; h[1] = h[2]; h[2] = h[3]; h[3] = h[4]; h[4] = hnew;
        float iw = g0 * (h[0] + h[4]) + g1 * (h[1] + h[3]) + g2 * h[2];
        iw = fmaxf(iw * dinv, EPS);
        if constexpr (CE || RE) {
            bool rin = !RE || (t >= 0 && t <= H - 1);
            if (!(c_in && rin)) iw = 0.f;   // zero-pad of transpose conv
        }

        ev[0] = ev[1]; em[0] = em[1]; ep[0] = ep[1];
        ev[1] = ev[2]; em[1] = em[2]; ep[1] = ep[2];
        ev[2] = ev[3]; em[2] = em[3]; ep[2] = ep[3];
        ev[3] = v;     em[3] = m1;    ep[3] = p1;

        float U0 = 0.f, U1 = 0.f, U2 = 0.f;
        float V0 = 0.f, V1 = 0.f, V2 = 0.f;
        float W0 = 0.f, W1 = 0.f, W2 = 0.f;
#pragma unroll
        for (int ch = 0; ch < NC; ch++) {
            float r = fco[ch][0] * em[0] + fco[ch][1] * ev[0] + fco[ch][2] * ep[0]
                    + fco[ch][3] * em[1] + fco[ch][4] * ev[1] + fco[ch][5] * ep[1]
                    + fco[ch][6] * em[2] + fco[ch][7] * ev[2] + fco[ch][8] * ep[2];
            float a = __builtin_amdgcn_exp2f(r * w2[ch] + b2[ch]);
            float z = iw * (1.f - 2.f * __builtin_amdgcn_rcpf(a + 1.f));
            U0 += fco[ch][0] * z; V0 += fco[ch][1] * z; W0 += fco[ch][2] * z;
            U1 += fco[ch][3] * z; V1 += fco[ch][4] * z; W1 += fco[ch][5] * z;
            U2 += fco[ch][6] * z; V2 += fco[ch][7] * z; W2 += fco[ch][8] * z;
        }

        // accumulate in UVW space; single +/-1 column shift per row
        float diffU = aU0 + U2, diffV = aV0 + V2, diffW = aW0 + W2;
        aU0 = aU1 + U1; aV0 = aV1 + V1; aW0 = aW1 + W1;
        aU1 = U0;       aV1 = V0;       aW1 = W0;
        float diff = __shfl_up(diffU, 1) + diffV + __shfl_down(diffW, 1);

        if (i >= 2 && c_st) {
            float eo = ev[0];      // est row t-1
            float fg = (eo - n0) * __builtin_amdgcn_rcpf(eo * eo + EPS);
            float est2 = eo - diff - lam * iw_prev * fg;
            float en = est2 + g * (n0 - est2);
            en = fminf(fmaxf(en, EPS), 1.f);
            op[(size_t)(t - 1) * W + c] = en;
        }
        iw_prev = iw;
    }
}

__global__ __launch_bounds__(64) void stage_kernel(
    const float* __restrict__ est, const float* __restrict__ noisy,
    const float* __restrict__ blockmax,
    const float* __restrict__ filt,
    const float* __restrict__ wv, const float* __restrict__ bv,
    const float* __restrict__ lamp, const float* __restrict__ gatep,
    const float* __restrict__ gauss,
    float* __restrict__ out)
{
    const int l = threadIdx.x;
    const int band = blockIdx.x;
    const int R = blockIdx.y * SLAB;
    const int b = blockIdx.z;

    const float* e  = est   + (size_t)b * H * W;
    const float* nz = noisy + (size_t)b * H * W;
    float*       op = out   + (size_t)b * H * W;

    const float g0 = sqrtf(gauss[0]);
    const float g1 = sqrtf(gauss[6]);
    const float g2 = sqrtf(gauss[12]);
    const float lam = lamp[0];
    const float g = __builtin_amdgcn_rcpf(1.f + __builtin_amdgcn_exp2f(-gatep[0] * LOG2E));

    float m = fmaxf(blockmax[b * NBLK + l], blockmax[b * NBLK + 64 + l]);
#pragma unroll
    for (int off = 32; off > 0; off >>= 1)
        m = fmaxf(m, __shfl_xor(m, off, 64));
    const float dinv = __builtin_amdgcn_rcpf(fmaxf(m, EPS));

    const bool ce = (band == 0) || (band == NBANDS - 1);
    const bool re = (blockIdx.y == 0) || (blockIdx.y == gridDim.y - 1);

    if (!ce && !re)      run_band<false, false>(e, nz, op, filt, wv, bv, lam, g, dinv, g0, g1, g2, l, band, R);
    else if (!ce)        run_band<false, true >(e, nz, op, filt, wv, bv, lam, g, dinv, g0, g1, g2, l, band, R);
    else if (!re)        run_band<true,  false>(e, nz, op, filt, wv, bv, lam, g, dinv, g0, g1, g2, l, band, R);
    else                 run_band<true,  true >(e, nz, op, filt, wv, bv, lam, g, dinv, g0, g1, g2, l, band, R);
}

extern "C" void kernel_launch(void* const* d_in, const int* in_sizes, int n_in,
                              void* d_out, int out_size, void* d_ws, size_t ws_size,
                              hipStream_t stream)
{
    const float* noisy   = (const float*)d_in[0];
    const float* filters = (const float*)d_in[1];  // [7][8][1][3][3]
    const float* wv      = (const float*)d_in[2];  // [7][8]
    const float* bv      = (const float*)d_in[3];  // [7][8]
    const float* lam     = (const float*)d_in[4];  // [7]
    const float* gate    = (const float*)d_in[5];  // [7]
    const float* gauss   = (const float*)d_in[6];  // [25]
    float* out = (float*)d_out;

    char* ws = (char*)d_ws;
    float* ws0      = (float*)ws;                    // 8 MB ping buffer
    float* blockmax = (float*)(ws + (8u << 20));     // 128*8 floats, rewritten each stage

    const float* cur = noisy;
    for (int s = 0; s < NS; s++) {
        float* nxt = (s % 2 == 0) ? out : ws0;  // odd stage count -> final lands in out
        gauss_max_kernel<<<dim3(W / GW, H / GR, NB), dim3(64, 4), 0, stream>>>(
            cur, gauss, blockmax);
        stage_kernel<<<dim3(NBANDS, H / SLAB, NB), dim3(64), 0, stream>>>(
            cur, noisy, blockmax,
            filters + s * NC * 9, wv + s * NC, bv + s * NC, lam + s, gate + s, gauss, nxt);
        cur = nxt;
    }
}

// Round 9
// 266.016 us; speedup vs baseline: 1.5678x; 1.2376x over previous
//
#include <hip/hip_runtime.h>
#include <hip/hip_bf16.h>

#define EPS 1e-6f
#define H 512
#define W 512
#define NB 8
#define NC 8
#define NS 7
#define LOG2E 1.4426950408889634f

typedef float v2f __attribute__((ext_vector_type(2)));

__device__ __forceinline__ int refl(int t, int n) {
    if (t < 0) t = -t;
    if (t >= n) t = 2 * n - 2 - t;
    return t;
}

// ---------------- Kernel A: gaussian-smoothed max only ----------------------------
#define GW 256
#define GR 8
#define NBLK ((W / GW) * (H / GR))   // 128 slots per image

__global__ __launch_bounds__(256) void gauss_max_kernel(
    const float* __restrict__ est, const float* __restrict__ gauss,
    float* __restrict__ blockmax)
{
    const int tx = threadIdx.x, ty = threadIdx.y;
    const int x0 = blockIdx.x * GW;
    const int R  = blockIdx.y * GR + ty * 2;     // this wave: output rows R, R+1
    const int b  = blockIdx.z;
    const float* e = est + (size_t)b * H * W;
    const int c0 = x0 + tx * 4;

    const float g0 = sqrtf(gauss[0]);
    const float g1 = sqrtf(gauss[6]);
    const float g2 = sqrtf(gauss[12]);

    float4 h0, h1, h2, h3, h4;
    float m = 0.f;

#pragma unroll
    for (int k = 0; k < 6; k++) {
        const float* row = e + refl(R - 2 + k, H) * W;
        float4 v = *(const float4*)&row[c0];
        float em2 = __shfl_up(v.z, 1);
        float em1 = __shfl_up(v.w, 1);
        float ep1 = __shfl_down(v.x, 1);
        float ep2 = __shfl_down(v.y, 1);
        if (tx == 0) {
            if (x0 == 0) { em2 = v.z; em1 = v.y; }
            else         { em2 = row[c0 - 2]; em1 = row[c0 - 1]; }
        }
        if (tx == 63) {
            if (x0 + GW == W) { ep1 = v.z; ep2 = v.y; }
            else              { ep1 = row[c0 + 4]; ep2 = row[c0 + 5]; }
        }
        float4 hc;
        hc.x = g0 * (em2 + v.z) + g1 * (em1 + v.y) + g2 * v.x;
        hc.y = g0 * (em1 + v.w) + g1 * (v.x + v.z) + g2 * v.y;
        hc.z = g0 * (v.x + ep1) + g1 * (v.y + v.w) + g2 * v.z;
        hc.w = g0 * (v.y + ep2) + g1 * (v.z + ep1) + g2 * v.w;
        h0 = h1; h1 = h2; h2 = h3; h3 = h4; h4 = hc;
        if (k >= 4) {
            float ux = g0 * (h0.x + h4.x) + g1 * (h1.x + h3.x) + g2 * h2.x;
            float uy = g0 * (h0.y + h4.y) + g1 * (h1.y + h3.y) + g2 * h2.y;
            float uz = g0 * (h0.z + h4.z) + g1 * (h1.z + h3.z) + g2 * h2.z;
            float uw = g0 * (h0.w + h4.w) + g1 * (h1.w + h3.w) + g2 * h2.w;
            m = fmaxf(m, fmaxf(fmaxf(ux, uy), fmaxf(uz, uw)));
        }
    }

#pragma unroll
    for (int off = 32; off > 0; off >>= 1)
        m = fmaxf(m, __shfl_xor(m, off, 64));
    __shared__ float wm[4];
    if (tx == 0) wm[ty] = m;
    __syncthreads();
    if (tx == 0 && ty == 0) {
        float mm = fmaxf(fmaxf(wm[0], wm[1]), fmaxf(wm[2], wm[3]));
        blockmax[b * NBLK + blockIdx.y * gridDim.x + blockIdx.x] = mm;
    }
}

// ---------------- Kernel B: register-streaming stage ------------------------------
// 1 wave = 64-col band (outputs lanes 3..60). No LDS. No neighbor shfls: the
// 5 horizontal taps are direct loads (reflect baked into 5 per-lane column
// indices; row base is uniform SALU). Channels packed in v2f -> v_pk_fma_f32.
#define SLAB 8
#define BANDW 58
#define NBANDS 9

__global__ __launch_bounds__(64) void stage_kernel(
    const float* __restrict__ est, const float* __restrict__ noisy,
    const float* __restrict__ blockmax,
    const float* __restrict__ filt,
    const float* __restrict__ wv, const float* __restrict__ bv,
    const float* __restrict__ lamp, const float* __restrict__ gatep,
    const float* __restrict__ gauss,
    float* __restrict__ out)
{
    const int l = threadIdx.x;
    const int band = blockIdx.x;
    const int R = blockIdx.y * SLAB;
    const int b = blockIdx.z;

    const float* e  = est   + (size_t)b * H * W;
    const float* nz = noisy + (size_t)b * H * W;
    float*       op = out   + (size_t)b * H * W;

    const int c = band * BANDW - 3 + l;
    const int ci0 = refl(c - 2, W), ci1 = refl(c - 1, W), ci2 = refl(c, W),
              ci3 = refl(c + 1, W), ci4 = refl(c + 2, W);
    const int cc = c < 0 ? 0 : (c > W - 1 ? W - 1 : c);
    const bool c_in = (c >= 0) && (c < W);
    const bool c_st = (l >= 3) && (l <= 60) && (c < W);

    // packed filters: fp[k][j] = {f[2j][k], f[2j+1][k]} (uniform -> SGPRs)
    v2f fp[9][4], w2p[4], b2p[4];
#pragma unroll
    for (int j = 0; j < 4; j++) {
#pragma unroll
        for (int k = 0; k < 9; k++)
            fp[k][j] = (v2f){filt[(2 * j) * 9 + k], filt[(2 * j + 1) * 9 + k]};
        w2p[j] = (v2f){wv[2 * j] * (2.f * LOG2E), wv[2 * j + 1] * (2.f * LOG2E)};
        b2p[j] = (v2f){bv[2 * j] * (2.f * LOG2E), bv[2 * j + 1] * (2.f * LOG2E)};
    }

    const float g0 = sqrtf(gauss[0]);
    const float g1 = sqrtf(gauss[6]);
    const float g2 = sqrtf(gauss[12]);
    const float lam = lamp[0];
    const float g = __builtin_amdgcn_rcpf(1.f + __builtin_amdgcn_exp2f(-gatep[0] * LOG2E));

    float m = fmaxf(blockmax[b * NBLK + l], blockmax[b * NBLK + 64 + l]);
#pragma unroll
    for (int off = 32; off > 0; off >>= 1)
        m = fmaxf(m, __shfl_xor(m, off, 64));
    const float dinv = __builtin_amdgcn_rcpf(fmaxf(m, EPS));

    // 5-tap row load (row index uniform -> SALU refl; 5 saddr loads, L1-friendly)
    auto ld5 = [&](int r, float& m2, float& m1, float& v, float& p1, float& p2) {
        const float* rb = e + (size_t)refl(r, H) * W;
        m2 = rb[ci0]; m1 = rb[ci1]; v = rb[ci2]; p1 = rb[ci3]; p2 = rb[ci4];
    };
    auto hof = [&](float m2, float m1, float v, float p1, float p2) -> float {
        return g0 * (m2 + p2) + g1 * (m1 + p1) + g2 * v;
    };
    auto ldn = [&](int r) -> float {
        int rr = r < 0 ? 0 : (r > H - 1 ? H - 1 : r);
        return nz[(size_t)rr * W + cc];
    };

    // prologue: h for rows R-3..R; est windows (m1,v,p1) rows R-2..R in slots 1..3
    float h[5];
    float wm1[4], wvv[4], wp1[4];
    {
        float m2, m1, v, p1, p2;
        ld5(R - 3, m2, m1, v, p1, p2); h[1] = hof(m2, m1, v, p1, p2);
        ld5(R - 2, m2, m1, v, p1, p2); h[2] = hof(m2, m1, v, p1, p2);
        wm1[1] = m1; wvv[1] = v; wp1[1] = p1;
        ld5(R - 1, m2, m1, v, p1, p2); h[3] = hof(m2, m1, v, p1, p2);
        wm1[2] = m1; wvv[2] = v; wp1[2] = p1;
        ld5(R - 0, m2, m1, v, p1, p2); h[4] = hof(m2, m1, v, p1, p2);
        wm1[3] = m1; wvv[3] = v; wp1[3] = p1;
    }
    // prefetch queues: est rows R+1..R+3 (5-tap tuples), noisy rows R-2..R
    float qm2[3], qm1[3], qv[3], qp1[3], qp2[3];
    ld5(R + 1, qm2[0], qm1[0], qv[0], qp1[0], qp2[0]);
    ld5(R + 2, qm2[1], qm1[1], qv[1], qp1[1], qp2[1]);
    ld5(R + 3, qm2[2], qm1[2], qv[2], qp1[2], qp2[2]);
    float nq0 = ldn(R - 2), nq1 = ldn(R - 1), nq2 = ldn(R);
    wm1[0] = 0.f; wvv[0] = 0.f; wp1[0] = 0.f; h[0] = 0.f;

    v2f aU0 = {0,0}, aV0 = {0,0}, aW0 = {0,0};
    v2f aU1 = {0,0}, aV1 = {0,0}, aW1 = {0,0};
    float iw_prev = 0.f;

#pragma unroll 2
    for (int i = 0; i < SLAB + 2; ++i) {
        const int t = R - 1 + i;

        // pop 5-tap tuple (row t+2); refill with row t+5 (3 iterations ahead)
        float m2 = qm2[0], m1 = qm1[0], v = qv[0], p1 = qp1[0], p2 = qp2[0];
        qm2[0] = qm2[1]; qm1[0] = qm1[1]; qv[0] = qv[1]; qp1[0] = qp1[1]; qp2[0] = qp2[1];
        qm2[1] = qm2[2]; qm1[1] = qm1[2]; qv[1] = qv[2]; qp1[1] = qp1[2]; qp2[1] = qp2[2];
        ld5(t + 5, qm2[2], qm1[2], qv[2], qp1[2], qp2[2]);
        float n0 = nq0; nq0 = nq1; nq1 = nq2; nq2 = ldn(t + 2);

        float hnew = hof(m2, m1, v, p1, p2);
        h[0] = h[1]; h[1] = h[2]; h[2] = h[3]; h[3] = h[4]; h[4] = hnew;
        float iw = fmaxf((g0 * (h[0] + h[4]) + g1 * (h[1] + h[3]) + g2 * h[2]) * dinv, EPS);
        const bool rin = (t >= 0) && (t < H);
        if (!(c_in && rin)) iw = 0.f;    // zero-pad of transpose conv

        wm1[0] = wm1[1]; wvv[0] = wvv[1]; wp1[0] = wp1[1];
        wm1[1] = wm1[2]; wvv[1] = wvv[2]; wp1[1] = wp1[2];
        wm1[2] = wm1[3]; wvv[2] = wvv[3]; wp1[2] = wp1[3];
        wm1[3] = m1;     wvv[3] = v;      wp1[3] = p1;

        // analysis conv on rows t-1..t+1 (slots 0..2), channel pairs in v2f
        float ew[9] = {wm1[0], wvv[0], wp1[0],
                       wm1[1], wvv[1], wp1[1],
                       wm1[2], wvv[2], wp1[2]};
        v2f r4[4] = {{0,0},{0,0},{0,0},{0,0}};
#pragma unroll
        for (int k = 0; k < 9; k++) {
            v2f es = (v2f){ew[k], ew[k]};
            r4[0] += fp[k][0] * es;
            r4[1] += fp[k][1] * es;
            r4[2] += fp[k][2] * es;
            r4[3] += fp[k][3] * es;
        }
        // tanh(w*r+b) in exp2 domain, z = iw * tanh
        v2f zp[4];
        v2f iwv = (v2f){iw, iw};
#pragma unroll
        for (int j = 0; j < 4; j++) {
            v2f wr = w2p[j] * r4[j] + b2p[j];
            float a0 = __builtin_amdgcn_exp2f(wr.x);
            float a1 = __builtin_amdgcn_exp2f(wr.y);
            v2f th = (v2f){1.f - 2.f * __builtin_amdgcn_rcpf(a0 + 1.f),
                           1.f - 2.f * __builtin_amdgcn_rcpf(a1 + 1.f)};
            zp[j] = iwv * th;
        }
        // synthesis partials (channel pairs)
        v2f U0 = {0,0}, V0 = {0,0}, W0 = {0,0};
        v2f U1 = {0,0}, V1 = {0,0}, W1 = {0,0};
        v2f U2 = {0,0}, V2 = {0,0}, W2 = {0,0};
#pragma unroll
        for (int j = 0; j < 4; j++) {
            U0 += fp[0][j] * zp[j]; V0 += fp[1][j] * zp[j]; W0 += fp[2][j] * zp[j];
            U1 += fp[3][j] * zp[j]; V1 += fp[4][j] * zp[j]; W1 += fp[5][j] * zp[j];
            U2 += fp[6][j] * zp[j]; V2 += fp[7][j] * zp[j]; W2 += fp[8][j] * zp[j];
        }
        v2f dU = aU0 + U2, dV = aV0 + V2, dW = aW0 + W2;
        aU0 = aU1 + U1; aV0 = aV1 + V1; aW0 = aW1 + W1;
        aU1 = U0;       aV1 = V0;       aW1 = W0;
        float dUs = dU.x + dU.y, dVs = dV.x + dV.y, dWs = dW.x + dW.y;
        float diff = __shfl_up(dUs, 1) + dVs + __shfl_down(dWs, 1);

        if (i >= 2 && c_st) {
            float eo = wvv[0];     // est row t-1, center tap
            float fg = (eo - n0) * __builtin_amdgcn_rcpf(eo * eo + EPS);
            float est2 = eo - diff - lam * iw_prev * fg;
            float en = est2 + g * (n0 - est2);
            en = fminf(fmaxf(en, EPS), 1.f);
            op[(size_t)(t - 1) * W + c] = en;
        }
        iw_prev = iw;
    }
}

extern "C" void kernel_launch(void* const* d_in, const int* in_sizes, int n_in,
                              void* d_out, int out_size, void* d_ws, size_t ws_size,
                              hipStream_t stream)
{
    const float* noisy   = (const float*)d_in[0];
    const float* filters = (const float*)d_in[1];  // [7][8][1][3][3]
    const float* wv      = (const float*)d_in[2];  // [7][8]
    const float* bv      = (const float*)d_in[3];  // [7][8]
    const float* lam     = (const float*)d_in[4];  // [7]
    const float* gate    = (const float*)d_in[5];  // [7]
    const float* gauss   = (const float*)d_in[6];  // [25]
    float* out = (float*)d_out;

    char* ws = (char*)d_ws;
    float* ws0      = (float*)ws;                    // 8 MB ping buffer
    float* blockmax = (float*)(ws + (8u << 20));     // 128*8 floats, rewritten each stage

    const float* cur = noisy;
    for (int s = 0; s < NS; s++) {
        float* nxt = (s % 2 == 0) ? out : ws0;  // odd stage count -> final lands in out
        gauss_max_kernel<<<dim3(W / GW, H / GR, NB), dim3(64, 4), 0, stream>>>(
            cur, gauss, blockmax);
        stage_kernel<<<dim3(NBANDS, H / SLAB, NB), dim3(64), 0, stream>>>(
            cur, noisy, blockmax,
            filters + s * NC * 9, wv + s * NC, bv + s * NC, lam + s, gate + s, gauss, nxt);
        cur = nxt;
    }
}